// Round 13
// baseline (138.501 us; speedup 1.0000x reference)
//
#include <hip/hip_runtime.h>

// GaussianSamplingPredict: B=1024, C=100, S=1000
//   L = cholesky(cov + 1e-6 I); t[b,s,d] = u[b,d] + sum_c z[s,c]*L[b,d,c]
//   out[b,d] = mean_s softmax_d(t[b,s,:])[d]
//
// R12: FUSED chol+pred (one kernel per batch). Lessons R7-R11: chol is
// latency/occupancy-bound (wall time ~ 1/occupancy); inner-loop micro-fixes
// (readlane, Pt) all lost. Fusion instead: pred's MFMA/VALU work from
// co-resident blocks fills chol's LDS-latency bubbles (m114 co-schedule),
// and the 29.4 MB Lb global roundtrip disappears (pack goes straight to
// MFMA B-frag registers from LDS M). red buffer overlays dead M -> LDS
// stays 40,448 B. chol internals = R7-exact (the empirical champion).

#define CC    100
#define SS    1000
#define EPSF  1e-6f
#define NB    16     // Cholesky panel width
#define NDT   7      // d-tiles: 7*16 = 112 >= 100
#define NCS   4      // c-steps: 4*32 = 128 >= 102
#define NST   63     // s-tiles: 63*16 = 1008 >= 1000
#define LOG2E 1.44269504088896340736f

typedef short  s8 __attribute__((ext_vector_type(8)));   // 8 bf16 (4 VGPR)
typedef float  f4 __attribute__((ext_vector_type(4)));

__device__ inline unsigned short f2bf(float x) {          // round-nearest-even
    unsigned u = __float_as_uint(x);
    return (unsigned short)((u + 0x7fffu + ((u >> 16) & 1u)) >> 16);
}
__device__ inline float bf2f(unsigned short h) {
    return __uint_as_float(((unsigned)h) << 16);
}

// ---------------- K0: pack z -> bf16 frags (+ ones at c=100,101) ----------------
// frag layout: [stile][cstep][lane][j]; lane l: s = stile*16+(l&15),
// c = cstep*32 + (l>>4)*8 + j.
__global__ __launch_bounds__(256)
void zconv_kernel(const float* __restrict__ z, unsigned short* __restrict__ zb) {
    const int stile = blockIdx.x;            // 0..62
    const int cs = threadIdx.x >> 6;
    const int l  = threadIdx.x & 63;
    const int s  = stile * 16 + (l & 15);
    const int c0 = cs * 32 + (l >> 4) * 8;
    unsigned short v[8];
    #pragma unroll
    for (int j = 0; j < 8; ++j) {
        const int c = c0 + j;
        float x = 0.0f;
        if (c < CC)      x = (s < SS) ? z[(size_t)s * CC + c] : 0.0f;
        else if (c <= CC + 1) x = 1.0f;          // u_hi / u_lo slots
        v[j] = f2bf(x);
    }
    uint4 pk;
    pk.x = (unsigned)v[0] | ((unsigned)v[1] << 16);
    pk.y = (unsigned)v[2] | ((unsigned)v[3] << 16);
    pk.z = (unsigned)v[4] | ((unsigned)v[5] << 16);
    pk.w = (unsigned)v[6] | ((unsigned)v[7] << 16);
    reinterpret_cast<uint4*>(zb)[(stile * NCS + cs) * 64 + l] = pk;
}

// R7-exact register-resident panel factorization (wave 0 only).
// Lane l holds cols l and l+64 of each panel row; __shfl broadcasts.
template<int NPAN>
__device__ inline void panel_factor(float* __restrict__ M, int jb, int l) {
    float P0r[NPAN], P1r[NPAN];
    const int i1 = l + 64;
    #pragma unroll
    for (int jj = 0; jj < NPAN; ++jj) {
        P0r[jj] = M[(jb + jj) * CC + l];
        P1r[jj] = (i1 < CC) ? M[(jb + jj) * CC + i1] : 0.0f;
    }
    #pragma unroll
    for (int jj = 0; jj < NPAN; ++jj) {
        const int j = jb + jj;
        const float dsrc  = (j & 64) ? P1r[jj] : P0r[jj];
        const float val   = __shfl(dsrc, j & 63);
        const float dinv  = rsqrtf(val);
        const float s     = val * dinv;
        const float dinv2 = dinv * dinv;
        #pragma unroll
        for (int kk = jj + 1; kk < NPAN; ++kk) {
            const int k = jb + kk;
            const float tsrc = (k & 64) ? P1r[jj] : P0r[jj];
            const float t = __shfl(tsrc, k & 63) * dinv2;
            P0r[kk] -= P0r[jj] * t;
            P1r[kk] -= P1r[jj] * t;
        }
        P0r[jj] = (l == j) ? s : ((l > j) ? P0r[jj] * dinv : P0r[jj]);
        P1r[jj] = (i1 == j) ? s : ((i1 > j) ? P1r[jj] * dinv : P1r[jj]);
    }
    #pragma unroll
    for (int jj = 0; jj < NPAN; ++jj) {
        M[(jb + jj) * CC + l] = P0r[jj];
        if (i1 < CC) M[(jb + jj) * CC + i1] = P1r[jj];
    }
}

// ---------------- fused: Cholesky + frag pack + MFMA pred ----------------
// Storage: M[x*100+y] = L[y][x] for y>=x.
__global__ __launch_bounds__(256, 2)
void gsp_kernel(const float* __restrict__ cov, const float* __restrict__ u,
                const unsigned short* __restrict__ zb, float* __restrict__ out) {
    __shared__ alignas(16) float M[CC * CC];   // 40,000 B; red overlays later
    const int tid = threadIdx.x;
    const int w   = tid >> 6;
    const int l   = tid & 63;
    const int b   = blockIdx.x;
    const int li  = l & 15;
    const int hi  = l >> 4;

    // ---- load cov (+eps I) ----
    const float4* c4 = reinterpret_cast<const float4*>(cov + (size_t)b * CC * CC);
    for (int t = tid; t < CC * CC / 4; t += 256)
        reinterpret_cast<float4*>(M)[t] = c4[t];
    __syncthreads();
    for (int d = tid; d < CC; d += 256) M[d * CC + d] += EPSF;
    __syncthreads();

    // ---- blocked Cholesky (R7-exact) ----
    for (int jb = 0; jb < CC; jb += NB) {
        const int jend = (jb + NB < CC) ? jb + NB : CC;

        if (w == 0) {
            if (jend - jb == NB) panel_factor<NB>(M, jb, l);
            else                 panel_factor<CC - (CC / NB) * NB>(M, jb, l); // 4
        }
        __syncthreads();

        // rank-16 trailing update, rows split across 4 waves; lane cols
        // i0 = jend+l, i1 = i0+64 cached in registers across rows.
        if (jend < CC) {
            const int i0 = jend + l;
            const int i1 = i0 + 64;
            float P0[NB], P1[NB];
            #pragma unroll
            for (int jj = 0; jj < NB; ++jj) {
                P0[jj] = (i0 < CC) ? M[(jb + jj) * CC + i0] : 0.0f;
                P1[jj] = (i1 < CC) ? M[(jb + jj) * CC + i1] : 0.0f;
            }
            #pragma unroll 2
            for (int k = jend + w; k < CC; k += 4) {
                float bk[NB];
                #pragma unroll
                for (int jj = 0; jj < NB; ++jj)
                    bk[jj] = M[(jb + jj) * CC + k];          // uniform bcast
                if (i0 < CC) {
                    float acc = M[k * CC + i0];
                    #pragma unroll
                    for (int jj = 0; jj < NB; ++jj) acc -= P0[jj] * bk[jj];
                    M[k * CC + i0] = acc;
                }
                if (i1 < CC) {
                    float acc = M[k * CC + i1];
                    #pragma unroll
                    for (int jj = 0; jj < NB; ++jj) acc -= P1[jj] * bk[jj];
                    M[k * CC + i1] = acc;
                }
            }
        }
        __syncthreads();
    }

    // ---- pack: M (LDS) -> per-thread MFMA B-frags (registers) ----
    // frag lane l: d = dt*16 + (l&15), c = cs*32 + (l>>4)*8 + j.
    //   c<100:  L[d][c]*LOG2E = M[c*100+d]*LOG2E (0 above diag / pad rows)
    //   c==100: bf16(u[d]*LOG2E) or -1e30 pad sentinel; c==101: residual
    float uv[NDT], uhi[NDT];
    #pragma unroll
    for (int dt = 0; dt < NDT; ++dt) {
        const int d = dt * 16 + li;
        const float t = (d < CC) ? u[(size_t)b * CC + d] * LOG2E : 0.0f;
        uv[dt]  = t;
        uhi[dt] = bf2f(f2bf(t));
    }
    s8 Bf[NDT][NCS];
    #pragma unroll
    for (int dt = 0; dt < NDT; ++dt) {
        const int d = dt * 16 + li;
        #pragma unroll
        for (int cs = 0; cs < NCS; ++cs) {
            const int c0 = cs * 32 + hi * 8;
            s8 r;
            #pragma unroll
            for (int j = 0; j < 8; ++j) {
                const int c = c0 + j;
                float x = 0.0f;
                if (c < CC) {
                    if (d < CC && c <= d) x = M[c * CC + d] * LOG2E;
                } else if (c == CC) {
                    x = (d < CC) ? uhi[dt] : -1e30f;
                } else if (c == CC + 1) {
                    if (d < CC) x = uv[dt] - uhi[dt];
                }
                r[j] = (short)f2bf(x);
            }
            Bf[dt][cs] = r;
        }
    }
    __syncthreads();   // last M reads done; M reusable as `red` below

    // ---- pred: MFMA matmul + base-2 softmax + mean ----
    float meanAcc[NDT][4];
    #pragma unroll
    for (int dt = 0; dt < NDT; ++dt)
        #pragma unroll
        for (int r = 0; r < 4; ++r) meanAcc[dt][r] = 0.0f;

    const s8* zb8 = reinterpret_cast<const s8*>(zb);

    for (int st = w; st < NST; st += 4) {
        s8 Af[NCS];
        #pragma unroll
        for (int cs = 0; cs < NCS; ++cs)
            Af[cs] = zb8[(st * NCS + cs) * 64 + l];

        f4 acc[NDT];
        #pragma unroll
        for (int dt = 0; dt < NDT; ++dt) acc[dt] = (f4){0.f, 0.f, 0.f, 0.f};

        // swapped operands: D[row=d][col=s]; lane: d = dt*16+hi*4+r, s = st*16+li
        #pragma unroll
        for (int cs = 0; cs < NCS; ++cs)
            #pragma unroll
            for (int dt = 0; dt < NDT; ++dt)
                acc[dt] = __builtin_amdgcn_mfma_f32_16x16x32_bf16(
                              Bf[dt][cs], Af[cs], acc[dt], 0, 0, 0);

        // base-2 softmax over d (no max-subtract; |logit| small, fp32-safe)
        float rs01 = 0.0f, rs23 = 0.0f;
        #pragma unroll
        for (int dt = 0; dt < NDT; ++dt) {
            acc[dt][0] = __builtin_amdgcn_exp2f(acc[dt][0]);
            acc[dt][1] = __builtin_amdgcn_exp2f(acc[dt][1]);
            acc[dt][2] = __builtin_amdgcn_exp2f(acc[dt][2]);
            acc[dt][3] = __builtin_amdgcn_exp2f(acc[dt][3]);
            rs01 += acc[dt][0] + acc[dt][1];
            rs23 += acc[dt][2] + acc[dt][3];
        }
        float rs = rs01 + rs23;
        rs += __shfl_xor(rs, 16);
        rs += __shfl_xor(rs, 32);
        const float wgt = (st * 16 + li < SS) ? __builtin_amdgcn_rcpf(rs) : 0.0f;
        #pragma unroll
        for (int dt = 0; dt < NDT; ++dt)
            #pragma unroll
            for (int r = 0; r < 4; ++r) meanAcc[dt][r] += acc[dt][r] * wgt;
    }

    // ---- reduce across the 16 li lanes (same d, different s); red = M ----
    float* red = M;
    #pragma unroll
    for (int dt = 0; dt < NDT; ++dt)
        #pragma unroll
        for (int r = 0; r < 4; ++r) {
            float v = meanAcc[dt][r];
            v += __shfl_xor(v, 1);
            v += __shfl_xor(v, 2);
            v += __shfl_xor(v, 4);
            v += __shfl_xor(v, 8);
            if (li == 0) red[w * (NDT * 16) + dt * 16 + hi * 4 + r] = v;
        }
    __syncthreads();
    if (tid < CC) {
        const float sum = red[tid] + red[NDT * 16 + tid] +
                          red[2 * NDT * 16 + tid] + red[3 * NDT * 16 + tid];
        out[(size_t)b * CC + tid] = sum * (1.0f / (float)SS);
    }
}

extern "C" void kernel_launch(void* const* d_in, const int* in_sizes, int n_in,
                              void* d_out, int out_size, void* d_ws, size_t ws_size,
                              hipStream_t stream) {
    const float* u   = (const float*)d_in[0];
    const float* cov = (const float*)d_in[1];
    const float* z   = (const float*)d_in[2];
    float* outp = (float*)d_out;
    const int B = in_sizes[0] / CC;          // 1024

    unsigned short* zb = (unsigned short*)d_ws;   // 258 KB

    zconv_kernel<<<dim3(NST), dim3(256), 0, stream>>>(z, zb);
    gsp_kernel  <<<dim3(B),   dim3(256), 0, stream>>>(cov, u, zb, outp);
}

// Round 14
// 117.364 us; speedup vs baseline: 1.1801x; 1.1801x over previous
//
#include <hip/hip_runtime.h>

// GaussianSamplingPredict: B=1024, C=100, S=1000
//   L = cholesky(cov + 1e-6 I); t[b,s,d] = u[b,d] + sum_c z[s,c]*L[b,d,c]
//   out[b,d] = mean_s softmax_d(t[b,s,:])[d]
//
// R13: revert to the proven R7 3-kernel config (114.7 us best; R8-R12 all
// regressed) + ONE change: classic lookahead in chol. Per panel iteration:
//  phase A: all 4 waves update only the NEXT panel's 16 rows; barrier;
//  phase B: wave 0 factors the next panel CONCURRENTLY with waves 1-3
//           updating the bulk trailing rows; barrier.
// Wave-0's serial ~3.2k-cyc shfl/rsqrt chain (previously ~25k cyc/block of
// other-waves-idle) now overlaps the bulk trailing. Row-level FMA order and
// per-row panel ordering unchanged -> absmax bit-identical 9.77e-4.

#define CC    100
#define SS    1000
#define EPSF  1e-6f
#define NB    16     // Cholesky panel width
#define NDT   7      // d-tiles: 7*16 = 112 >= 100
#define NCS   4      // c-steps: 4*32 = 128 >= 102
#define NST   63     // s-tiles: 63*16 = 1008 >= 1000
#define LOG2E 1.44269504088896340736f

typedef short  s8 __attribute__((ext_vector_type(8)));   // 8 bf16 (4 VGPR)
typedef float  f4 __attribute__((ext_vector_type(4)));

__device__ inline unsigned short f2bf(float x) {          // round-nearest-even
    unsigned u = __float_as_uint(x);
    return (unsigned short)((u + 0x7fffu + ((u >> 16) & 1u)) >> 16);
}
__device__ inline float bf2f(unsigned short h) {
    return __uint_as_float(((unsigned)h) << 16);
}

// ---------------- K0: pack z -> bf16 frags (+ ones at c=100,101) ----------------
// frag layout: [stile][cstep][lane][j]; lane l: s = stile*16+(l&15),
// c = cstep*32 + (l>>4)*8 + j.
__global__ __launch_bounds__(256)
void zconv_kernel(const float* __restrict__ z, unsigned short* __restrict__ zb) {
    const int stile = blockIdx.x;            // 0..62
    const int cs = threadIdx.x >> 6;
    const int l  = threadIdx.x & 63;
    const int s  = stile * 16 + (l & 15);
    const int c0 = cs * 32 + (l >> 4) * 8;
    unsigned short v[8];
    #pragma unroll
    for (int j = 0; j < 8; ++j) {
        const int c = c0 + j;
        float x = 0.0f;
        if (c < CC)      x = (s < SS) ? z[(size_t)s * CC + c] : 0.0f;
        else if (c <= CC + 1) x = 1.0f;          // u_hi / u_lo slots
        v[j] = f2bf(x);
    }
    uint4 pk;
    pk.x = (unsigned)v[0] | ((unsigned)v[1] << 16);
    pk.y = (unsigned)v[2] | ((unsigned)v[3] << 16);
    pk.z = (unsigned)v[4] | ((unsigned)v[5] << 16);
    pk.w = (unsigned)v[6] | ((unsigned)v[7] << 16);
    reinterpret_cast<uint4*>(zb)[(stile * NCS + cs) * 64 + l] = pk;
}

// R7-exact register-resident panel factorization (wave 0 only).
// Lane l holds cols l and l+64 of each panel row; __shfl broadcasts.
template<int NPAN>
__device__ inline void panel_factor(float* __restrict__ M, int jb, int l) {
    float P0r[NPAN], P1r[NPAN];
    const int i1 = l + 64;
    #pragma unroll
    for (int jj = 0; jj < NPAN; ++jj) {
        P0r[jj] = M[(jb + jj) * CC + l];
        P1r[jj] = (i1 < CC) ? M[(jb + jj) * CC + i1] : 0.0f;
    }
    #pragma unroll
    for (int jj = 0; jj < NPAN; ++jj) {
        const int j = jb + jj;
        const float dsrc  = (j & 64) ? P1r[jj] : P0r[jj];
        const float val   = __shfl(dsrc, j & 63);
        const float dinv  = rsqrtf(val);
        const float s     = val * dinv;
        const float dinv2 = dinv * dinv;
        #pragma unroll
        for (int kk = jj + 1; kk < NPAN; ++kk) {
            const int k = jb + kk;
            const float tsrc = (k & 64) ? P1r[jj] : P0r[jj];
            const float t = __shfl(tsrc, k & 63) * dinv2;
            P0r[kk] -= P0r[jj] * t;
            P1r[kk] -= P1r[jj] * t;
        }
        P0r[jj] = (l == j) ? s : ((l > j) ? P0r[jj] * dinv : P0r[jj]);
        P1r[jj] = (i1 == j) ? s : ((i1 > j) ? P1r[jj] * dinv : P1r[jj]);
    }
    #pragma unroll
    for (int jj = 0; jj < NPAN; ++jj) {
        M[(jb + jj) * CC + l] = P0r[jj];
        if (i1 < CC) M[(jb + jj) * CC + i1] = P1r[jj];
    }
}

// One trailing-update row k w.r.t. panel jb, lane cols i0/i1 cached in P0/P1.
__device__ inline void trail_row(float* __restrict__ M, int jb, int k,
                                 int i0, int i1,
                                 const float* __restrict__ P0,
                                 const float* __restrict__ P1) {
    float bk[NB];
    #pragma unroll
    for (int jj = 0; jj < NB; ++jj)
        bk[jj] = M[(jb + jj) * CC + k];          // uniform bcast
    if (i0 < CC) {
        float acc = M[k * CC + i0];
        #pragma unroll
        for (int jj = 0; jj < NB; ++jj) acc -= P0[jj] * bk[jj];
        M[k * CC + i0] = acc;
    }
    if (i1 < CC) {
        float acc = M[k * CC + i1];
        #pragma unroll
        for (int jj = 0; jj < NB; ++jj) acc -= P1[jj] * bk[jj];
        M[k * CC + i1] = acc;
    }
}

// ---------------- K1: lookahead blocked Cholesky (4 waves) + frag pack --------
// Storage: M[x*100+y] = L[y][x] for y>=x.
__global__ __launch_bounds__(256, 4)
void chol_kernel(const float* __restrict__ cov, const float* __restrict__ u,
                 unsigned short* __restrict__ Lb) {
    __shared__ float M[CC * CC];
    const int tid = threadIdx.x;
    const int w   = tid >> 6;
    const int l   = tid & 63;
    const int b   = blockIdx.x;

    const float4* c4 = reinterpret_cast<const float4*>(cov + (size_t)b * CC * CC);
    for (int t = tid; t < CC * CC / 4; t += 256)
        reinterpret_cast<float4*>(M)[t] = c4[t];
    __syncthreads();
    for (int d = tid; d < CC; d += 256) M[d * CC + d] += EPSF;
    __syncthreads();

    // prologue: factor panel 0
    if (w == 0) panel_factor<NB>(M, 0, l);
    __syncthreads();

    // lookahead loop: for each factored panel jb (jend < CC):
    //  A) all waves update next-panel rows jend..nend-1
    //  B) wave 0 factors panel jend || waves 1-3 update bulk rows nend..99
    for (int jb = 0; jb + NB < CC; jb += NB) {
        const int jend = jb + NB;
        const int nend = (jend + NB < CC) ? jend + NB : CC;

        // per-wave column cache for panel jb (cols i0 = jend+l, i1 = i0+64)
        const int i0 = jend + l;
        const int i1 = i0 + 64;
        float P0[NB], P1[NB];
        #pragma unroll
        for (int jj = 0; jj < NB; ++jj) {
            P0[jj] = (i0 < CC) ? M[(jb + jj) * CC + i0] : 0.0f;
            P1[jj] = (i1 < CC) ? M[(jb + jj) * CC + i1] : 0.0f;
        }

        // ---- phase A: next-panel rows (16 rows, 4 per wave) ----
        for (int k = jend + w; k < nend; k += 4)
            trail_row(M, jb, k, i0, i1, P0, P1);
        __syncthreads();

        // ---- phase B: factor next panel || bulk trailing ----
        if (w == 0) {
            if (nend - jend == NB) panel_factor<NB>(M, jend, l);
            else                   panel_factor<CC - (CC / NB) * NB>(M, jend, l);
        } else {
            #pragma unroll 2
            for (int k = nend + (w - 1); k < CC; k += 3)
                trail_row(M, jb, k, i0, i1, P0, P1);
        }
        __syncthreads();
    }

    // pack frags (28 over 4 waves): lane l: d = dt*16+(l&15),
    // c = cs*32+(l>>4)*8+j.
    //   c<100:  L[d][c]*LOG2E (0 above diagonal / pad rows)
    //   c==100: bf16(u[d]*LOG2E), or -1e30 for pad rows d>=100
    //   c==101: residual u*LOG2E - u_hi (0 for pad rows)
    const int tx = l & 15;
    const int ty = l >> 4;
    unsigned short* outp = Lb + (size_t)b * (NDT * NCS * 64 * 8);
    for (int f = w; f < NDT * NCS; f += 4) {
        const int dt = f >> 2, cs = f & 3;
        const int d  = dt * 16 + tx;
        const int c0 = cs * 32 + ty * 8;
        unsigned short v[8];
        #pragma unroll
        for (int j = 0; j < 8; ++j) {
            const int c = c0 + j;
            float x = 0.0f;
            if (c < CC) {
                if (d < CC && c <= d) x = M[c * CC + d] * LOG2E;
            } else if (c == CC) {
                if (d < CC) x = bf2f(f2bf(u[(size_t)b * CC + d] * LOG2E));
                else        x = -1e30f;              // pad row kill switch
            } else if (c == CC + 1) {
                if (d < CC) {
                    const float t = u[(size_t)b * CC + d] * LOG2E;
                    x = t - bf2f(f2bf(t));           // residual
                }
            }
            v[j] = f2bf(x);
        }
        uint4 pk;
        pk.x = (unsigned)v[0] | ((unsigned)v[1] << 16);
        pk.y = (unsigned)v[2] | ((unsigned)v[3] << 16);
        pk.z = (unsigned)v[4] | ((unsigned)v[5] << 16);
        pk.w = (unsigned)v[6] | ((unsigned)v[7] << 16);
        reinterpret_cast<uint4*>(outp)[f * 64 + l] = pk;
    }
}

// ---------------- K2: MFMA matmul + base-2 softmax + mean ----------------
__global__ __launch_bounds__(256, 1)
void pred_kernel(const unsigned short* __restrict__ Lb,
                 const unsigned short* __restrict__ zb,
                 float* __restrict__ out) {
    __shared__ float red[4 * NDT * 16];
    const int tid = threadIdx.x, b = blockIdx.x;
    const int w  = tid >> 6;
    const int l  = tid & 63;
    const int li = l & 15;
    const int hi = l >> 4;

    // persistent L-frags: 28 x 4 VGPR = 112 VGPR
    s8 Bf[NDT][NCS];
    const s8* Lb8 = reinterpret_cast<const s8*>(Lb + (size_t)b * (NDT * NCS * 64 * 8));
    #pragma unroll
    for (int dt = 0; dt < NDT; ++dt)
        #pragma unroll
        for (int cs = 0; cs < NCS; ++cs)
            Bf[dt][cs] = Lb8[(dt * NCS + cs) * 64 + l];

    float meanAcc[NDT][4];
    #pragma unroll
    for (int dt = 0; dt < NDT; ++dt)
        #pragma unroll
        for (int r = 0; r < 4; ++r) meanAcc[dt][r] = 0.0f;

    const s8* zb8 = reinterpret_cast<const s8*>(zb);

    for (int st = w; st < NST; st += 4) {
        s8 Af[NCS];
        #pragma unroll
        for (int cs = 0; cs < NCS; ++cs)
            Af[cs] = zb8[(st * NCS + cs) * 64 + l];

        f4 acc[NDT];
        #pragma unroll
        for (int dt = 0; dt < NDT; ++dt) acc[dt] = (f4){0.f, 0.f, 0.f, 0.f};

        // swapped operands: D[row=d][col=s]; lane: d = dt*16+hi*4+r, s = st*16+li
        #pragma unroll
        for (int cs = 0; cs < NCS; ++cs)
            #pragma unroll
            for (int dt = 0; dt < NDT; ++dt)
                acc[dt] = __builtin_amdgcn_mfma_f32_16x16x32_bf16(
                              Bf[dt][cs], Af[cs], acc[dt], 0, 0, 0);

        // base-2 softmax over d (no max-subtract; |logit| small, fp32-safe)
        float rs01 = 0.0f, rs23 = 0.0f;
        #pragma unroll
        for (int dt = 0; dt < NDT; ++dt) {
            acc[dt][0] = __builtin_amdgcn_exp2f(acc[dt][0]);
            acc[dt][1] = __builtin_amdgcn_exp2f(acc[dt][1]);
            acc[dt][2] = __builtin_amdgcn_exp2f(acc[dt][2]);
            acc[dt][3] = __builtin_amdgcn_exp2f(acc[dt][3]);
            rs01 += acc[dt][0] + acc[dt][1];
            rs23 += acc[dt][2] + acc[dt][3];
        }
        float rs = rs01 + rs23;
        rs += __shfl_xor(rs, 16);
        rs += __shfl_xor(rs, 32);
        const float wgt = (st * 16 + li < SS) ? __builtin_amdgcn_rcpf(rs) : 0.0f;
        #pragma unroll
        for (int dt = 0; dt < NDT; ++dt)
            #pragma unroll
            for (int r = 0; r < 4; ++r) meanAcc[dt][r] += acc[dt][r] * wgt;
    }

    // reduce across the 16 li lanes (same d, different s)
    #pragma unroll
    for (int dt = 0; dt < NDT; ++dt)
        #pragma unroll
        for (int r = 0; r < 4; ++r) {
            float v = meanAcc[dt][r];
            v += __shfl_xor(v, 1);
            v += __shfl_xor(v, 2);
            v += __shfl_xor(v, 4);
            v += __shfl_xor(v, 8);
            if (li == 0) red[w * (NDT * 16) + dt * 16 + hi * 4 + r] = v;
        }
    __syncthreads();
    if (tid < CC) {
        const float sum = red[tid] + red[NDT * 16 + tid] +
                          red[2 * NDT * 16 + tid] + red[3 * NDT * 16 + tid];
        out[(size_t)b * CC + tid] = sum * (1.0f / (float)SS);
    }
}

extern "C" void kernel_launch(void* const* d_in, const int* in_sizes, int n_in,
                              void* d_out, int out_size, void* d_ws, size_t ws_size,
                              hipStream_t stream) {
    const float* u   = (const float*)d_in[0];
    const float* cov = (const float*)d_in[1];
    const float* z   = (const float*)d_in[2];
    float* outp = (float*)d_out;
    const int B = in_sizes[0] / CC;          // 1024

    unsigned short* zb = (unsigned short*)d_ws;                       // 258 KB
    unsigned short* Lbf = (unsigned short*)((char*)d_ws + (1 << 20)); // 29.4 MB

    zconv_kernel<<<dim3(NST), dim3(256), 0, stream>>>(z, zb);
    chol_kernel <<<dim3(B),   dim3(256), 0, stream>>>(cov, u, Lbf);
    pred_kernel <<<dim3(B),   dim3(256), 0, stream>>>(Lbf, zb, outp);
}